// Round 2
// baseline (217.358 us; speedup 1.0000x reference)
//
#include <hip/hip_runtime.h>
#include <math.h>

#define NB 4096

// ---- workspace layout ----
// ints:
#define LEAFo  0                    // [3 idx][4 b][8 leaf] * 32  (128B spacing)
#define MASTo  3072                 // [3 idx][4 b] * 32
#define RELo   3456                 // [4 b][8 leaf] * 32
#define GHo    4480                 // [4 b][4096] histogram (low16: count, high16: cursor)
#define MEMSET_BYTES 83456          // 20864 ints
// floats:
#define TBLo   20864                // [256 blocks][64 chunk][194] per-block chunk tables
#define Ro     3199360              // [4 b][64 chunk][194] reduced tables

__device__ __forceinline__ void gst(float* p, float v) {
    __hip_atomic_store(p, v, __ATOMIC_RELAXED, __HIP_MEMORY_SCOPE_AGENT);
}

__device__ __forceinline__ int bucket_of(float v) {
    int k = (int)((v + 16.0f) * 128.0f);
    k = k < 0 ? 0 : k;
    k = k > (NB - 1) ? (NB - 1) : k;
    return k;
}

// Per-batch tree barrier: 64 contenders = 8 leaves x 8, release on 8 spread
// lines per batch. Batches decouple (batch 0 never waits on batch 3).
__device__ __forceinline__ void gbar(int* wsi, int idx, int b, int t6) {
    __syncthreads();
    if (threadIdx.x == 0) {
        int leaf = t6 & 7;
        bool bcast = false;
        int old = __hip_atomic_fetch_add(wsi + LEAFo + ((idx * 4 + b) * 8 + leaf) * 32, 1,
                                         __ATOMIC_RELAXED, __HIP_MEMORY_SCOPE_AGENT);
        if (old == 7) {
            int m = __hip_atomic_fetch_add(wsi + MASTo + (idx * 4 + b) * 32, 1,
                                           __ATOMIC_RELAXED, __HIP_MEMORY_SCOPE_AGENT);
            if (m == 7) {
#pragma unroll
                for (int i = 0; i < 8; i++)
                    __hip_atomic_store(wsi + RELo + (b * 8 + i) * 32, idx + 1,
                                       __ATOMIC_RELAXED, __HIP_MEMORY_SCOPE_AGENT);
                bcast = true;
            }
        }
        if (!bcast) {
            const int* myrel = wsi + RELo + (b * 8 + (t6 & 7)) * 32;
            while (__hip_atomic_load(myrel, __ATOMIC_RELAXED, __HIP_MEMORY_SCOPE_AGENT) <= idx)
                __builtin_amdgcn_s_sleep(1);
        }
    }
    __syncthreads();
}

// Restructured: VG (gamma@v per pixel) never leaves registers. Each block
// accumulates its 64 pixels' per-chunk contributions into an LDS table
// [64 chunks][194] (cols 0..63: sum(v), 64..127: sum(v*e^a), 128..191:
// sum(v*a), 192: sum(e^a), 193: sum(a)), writes it coalesced; a reduction
// phase sums the 64 block tables per batch. Removes the 8MB VG round-trip,
// the random permuted gather, and the sort scatter entirely.
__global__ __launch_bounds__(1024, 1) void k_fused(
        const float* __restrict__ x,
        const float* __restrict__ Wq, const float* __restrict__ bq,
        const float* __restrict__ Wk, const float* __restrict__ bk,
        const float* __restrict__ wcq, const float* __restrict__ wck,
        const float* __restrict__ Wv, const float* __restrict__ bv,
        const float* __restrict__ Wg, const float* __restrict__ bg,
        float* __restrict__ ws, float* __restrict__ out) {
    __shared__ float smem[13824];       // 55.3 KB
    int tid = threadIdx.x;
    int bid = blockIdx.x;
    int b = bid >> 6, t6 = bid & 63;
    int* wsi = (int*)ws;

    float myA = 0.f, myD = 0.f;         // a,d for pixel t6*64+tid (tid<64)
    int   myQ = 0;                      // snapped split chunk for own column j
    float vg[4];                        // VG[o, pixel nl0..nl0+3] stays in regs

    // ===== Phase A: weight prep (redundant) + projections + VG in registers =====
    {
        float* xt  = smem;              // [64][72] = 4608
        float* wt  = smem + 4608;       // [64][72]: wt[c][o] = Wvg[o][c]
        float* wgT = smem + 9216;       // [64][65]: wgT[m*65+o] = Wg[o][m] (padded)
        float* wqe = smem + 13376, *wke = smem + 13440, *bvg = smem + 13504, *misc = smem + 13568;
        // 1) x tile prefetch into registers (HBM latency overlaps Wg staging)
        const float4* xb4 = (const float4*)(x + (size_t)b * 64 * 4096);
        float4 xr;
        {
            int c = tid >> 4, nl4 = tid & 15;
            xr = xb4[c * 1024 + t6 * 16 + nl4];
        }
        // 2) stage Wg transposed into LDS (coalesced global read, padded LDS writes)
        {
            const float4* wg4 = (const float4*)Wg;
            int o = tid >> 4, q4 = tid & 15;
            float4 g = wg4[tid];
            int m0 = q4 * 4;
            wgT[(m0 + 0) * 65 + o] = g.x; wgT[(m0 + 1) * 65 + o] = g.y;
            wgT[(m0 + 2) * 65 + o] = g.z; wgT[(m0 + 3) * 65 + o] = g.w;
        }
        if (tid < 64) {
            float s1 = 0.f, s2 = 0.f;
            for (int o = 0; o < 16; o++) { s1 += wcq[o] * Wq[o * 64 + tid]; s2 += wck[o] * Wk[o * 64 + tid]; }
            wqe[tid] = s1; wke[tid] = s2;
        } else if (tid == 64) {
            float s = 0.f; for (int o = 0; o < 16; o++) s += wcq[o] * bq[o]; misc[0] = s;
        } else if (tid == 65) {
            float s = 0.f; for (int o = 0; o < 16; o++) s += wck[o] * bk[o]; misc[1] = s;
        }
        // 3) store x tile to LDS
        {
            int c = tid >> 4, nl4 = tid & 15;
            *(float4*)&xt[c * 72 + nl4 * 4] = xr;
        }
        __syncthreads();
        // 4) Wvg = Wg @ Wv from LDS-transposed Wg (conflict-free) + Wv broadcast
        {
            int o = tid & 63, c0 = (tid >> 6) * 4;
            float acc[4];
#pragma unroll
            for (int k = 0; k < 4; k++) acc[k] = 0.f;
            for (int m = 0; m < 64; m++) {
                float wg = wgT[m * 65 + o];
                float4 a0 = *(const float4*)(Wv + m * 64 + c0);   // wave-uniform -> broadcast
                acc[0] += wg * a0.x; acc[1] += wg * a0.y; acc[2] += wg * a0.z; acc[3] += wg * a0.w;
            }
#pragma unroll
            for (int k = 0; k < 4; k++) wt[(c0 + k) * 72 + o] = acc[k];
        }
        // bvg = Wg @ bv from the LDS transpose
        if (tid < 64) {
            float s3 = 0.f;
            for (int m = 0; m < 64; m++) s3 += wgT[m * 65 + tid] * bv[m];
            bvg[tid] = s3;
        }
        __syncthreads();
        if (tid < 64) {
            float s1 = misc[0], s2 = misc[1];
            for (int c = 0; c < 64; c++) {
                float xv = xt[c * 72 + tid];
                s1 += wqe[c] * xv; s2 += wke[c] * xv;
            }
            myA = s1; myD = s2;                              // both stay in registers
            atomicAdd(&wsi[GHo + b * 4096 + bucket_of(s1)], 1);
        }
        {
            int o = tid & 63, nl0 = (tid >> 6) * 4;
            float bo = bvg[o];
#pragma unroll
            for (int k = 0; k < 4; k++) vg[k] = bo;
            for (int c = 0; c < 64; c++) {
                float wv = wt[c * 72 + o];
                const float* xr2 = &xt[c * 72 + nl0];
#pragma unroll
                for (int k = 0; k < 4; k++) vg[k] += wv * xr2[k];
            }
        }
    }
    gbar(wsi, 0, b, t6);

    // ===== Phase B: per-block shfl scan + own-pixel rank/chunk + split lookup =====
    {
        unsigned int* hist = (unsigned int*)smem;          // [4096] bucket starts
        unsigned int* wtot = hist + 4096;                  // [16]
        int*   chkL  = (int*)(smem + 13440);               // [64] pixel -> chunk
        float* expaL = smem + 13504;                       // [64] e^a
        float* avalL = smem + 13568;                       // [64] a
        int* gh_b = wsi + GHo + b * 4096;
#pragma unroll 4
        for (int i = tid; i < NB; i += 1024) hist[i] = (unsigned int)gh_b[i] & 0xFFFFu;
        __syncthreads();
        int lane = tid & 63, w = tid >> 6;
        unsigned int s = 0u; int base = tid * 4;
#pragma unroll
        for (int k = 0; k < 4; k++) s += hist[base + k];
        unsigned int inc = s;
        for (int off = 1; off < 64; off <<= 1) {
            unsigned int u = __shfl_up(inc, off);
            if (lane >= off) inc += u;
        }
        if (lane == 63) wtot[w] = inc;
        __syncthreads();
        unsigned int run = inc - s;
        for (int w2 = 0; w2 < w; w2++) run += wtot[w2];
        for (int k = 0; k < 4; k++) {
            unsigned int h = hist[base + k];
            hist[base + k] = run;       // hist now holds bucket starts
            run += h;
        }
        __syncthreads();
        if (tid < 64) {
            // split lookup for own output column j = t6*64+tid (d in register)
            myQ = ((int)hist[bucket_of(-myD)] + 32) >> 6;
            // own pixel's rank via bucket start + packed cursor (exact 64/chunk)
            int kb = bucket_of(myA);
            int old = atomicAdd(&gh_b[kb], 0x10000);
            int r = (int)hist[kb] + (old >> 16);
            chkL[tid]  = r >> 6;
            expaL[tid] = expf(myA);
            avalL[tid] = myA;
        }
        __syncthreads();
    }

    // ===== Phase C: LDS chunk-table accumulation from VG registers =====
    {
        float* tbl   = smem;                               // [64][194] = 12416
        int*   chkL  = (int*)(smem + 13440);
        float* expaL = smem + 13504;
        float* avalL = smem + 13568;
        for (int i = tid; i < 12416; i += 1024) tbl[i] = 0.f;
        __syncthreads();
        int o = tid & 63, nl0 = (tid >> 6) * 4;
#pragma unroll
        for (int k = 0; k < 4; k++) {
            int p = nl0 + k;
            int ch = chkL[p];
            float v = vg[k];
            atomicAdd(&tbl[ch * 194 + o],       v);
            atomicAdd(&tbl[ch * 194 + 64 + o],  v * expaL[p]);
            atomicAdd(&tbl[ch * 194 + 128 + o], v * avalL[p]);
        }
        if (tid < 64) {
            int ch = chkL[tid];
            atomicAdd(&tbl[ch * 194 + 192], expaL[tid]);
            atomicAdd(&tbl[ch * 194 + 193], avalL[tid]);
        }
        __syncthreads();
        float* dst = ws + TBLo + (size_t)bid * 12416;
        for (int i = tid; i < 12416; i += 1024) gst(&dst[i], tbl[i]);
    }
    gbar(wsi, 1, b, t6);

    // ===== Phase R: reduce chunk t6 across the batch's 64 block tables =====
    {
        float* part = smem;                                // [4][208]
        int g = tid / 194;
        int col = tid - g * 194;
        if (g < 4) {
            const float* src = ws + TBLo + (size_t)(b * 64) * 12416 + t6 * 194 + col;
            float s = 0.f;
#pragma unroll
            for (int t = 0; t < 16; t++) s += src[(size_t)(g * 16 + t) * 12416];
            part[g * 208 + col] = s;
        }
        __syncthreads();
        if (tid < 194) {
            float s = part[tid] + part[208 + tid] + part[416 + tid] + part[624 + tid];
            gst(&ws[Ro + (size_t)(b * 64 + t6) * 194 + tid], s);
        }
    }
    gbar(wsi, 2, b, t6);

    // ===== Phase F: per-block chunk-prefix (unified 194 cols) + output =====
    {
        float* CP     = smem;                  // [65][195] = 12675
        float* djs    = smem + 12675;          // [64]
        float* edjs   = smem + 12739;          // [64]
        float* invden = smem + 12803;          // [64]
        int*   qarr   = (int*)(smem + 12867);  // [64]
        float* bgs    = smem + 12931;          // [64]
        if (tid < 194) {
            float v[64];
#pragma unroll
            for (int ch = 0; ch < 64; ch++) v[ch] = ws[Ro + (size_t)(b * 64 + ch) * 194 + tid];
            float r = 0.f;
#pragma unroll
            for (int q = 0; q < 64; q++) { CP[q * 195 + tid] = r; r += v[q]; }
            CP[64 * 195 + tid] = r;
        }
        if (tid < 64) bgs[tid] = bg[tid];
        __syncthreads();
        int j0 = t6 * 64;
        if (tid < 64) {
            float dj = myD;
            float edj = expf(dj);
            int q = myQ;
            float den = 1.5f * ((CP[64 * 195 + 193] - CP[q * 195 + 193])
                                + dj * (float)(4096 - 64 * q)
                                - (float)(64 * q) + edj * CP[q * 195 + 192]);
            qarr[tid] = q; djs[tid] = dj; edjs[tid] = edj; invden[tid] = 1.0f / den;
        }
        __syncthreads();
        {
            int jl = tid & 63, cq = tid >> 6;
            float dj = djs[jl], edj = edjs[jl], inv = invden[jl];
            int qb = qarr[jl] * 195;
#pragma unroll
            for (int cc = cq; cc < 64; cc += 16) {
                float c1 = CP[qb + cc], c2 = CP[qb + 64 + cc], c3 = CP[qb + 128 + cc];
                float t1 = CP[64 * 195 + cc], t3 = CP[64 * 195 + 128 + cc];
                float num = (t3 - c3) + dj * t1 - (1.0f + dj) * c1 + edj * c2;
                out[((size_t)(b * 64 + cc)) * 4096 + j0 + jl] = num * inv + bgs[cc];
            }
        }
    }
}

extern "C" void kernel_launch(void* const* d_in, const int* in_sizes, int n_in,
                              void* d_out, int out_size, void* d_ws, size_t ws_size,
                              hipStream_t stream) {
    const float* x   = (const float*)d_in[0];
    const float* Wq  = (const float*)d_in[1];
    const float* bq  = (const float*)d_in[2];
    const float* Wk  = (const float*)d_in[3];
    const float* bk  = (const float*)d_in[4];
    const float* wcq = (const float*)d_in[5];
    const float* wck = (const float*)d_in[6];
    const float* Wv  = (const float*)d_in[7];
    const float* bv  = (const float*)d_in[8];
    const float* Wg  = (const float*)d_in[9];
    const float* bg  = (const float*)d_in[10];
    float* ws  = (float*)d_ws;
    float* out = (float*)d_out;

    hipMemsetAsync(d_ws, 0, MEMSET_BYTES, stream);
    k_fused<<<256, 1024, 0, stream>>>(x, Wq, bq, Wk, bk, wcq, wck, Wv, bv, Wg, bg, ws, out);
}

// Round 4
// 109.639 us; speedup vs baseline: 1.9825x; 1.9825x over previous
//
#include <hip/hip_runtime.h>
#include <math.h>

#define NB 4096

// ---- workspace layout ----
// ints:
#define LEAFo  0                    // [3 idx][4 b][8 leaf] * 32  (128B spacing)
#define MASTo  3072                 // [3 idx][4 b] * 32
#define RELo   3456                 // [4 b][8 leaf] * 32
#define GHo    4480                 // [4 b][4096] histogram (low16: count, high16: cursor)
#define ZERO_F4 5216                // 20864 ints = 5216 float4, zeroed by k_prep
// floats:
#define WTo    20864                // [64 c][64 o]  Wvg in wt layout (from k_prep)
#define BVGo   24960                // [64]
#define WQEo   25024                // [64]
#define WKEo   25088                // [64]
#define MISCo  25152                // [2]
#define VGo    25216                // B*4096*64
#define ASo    1073792              // sorted a
#define PERMo  1090176              // int
#define Po     1106560              // chunk partials [b][64ch][192]
#define PSEAo  1155712              // [b][64]
#define PSAo   1155968              // [b][64]

__device__ __forceinline__ void gst(float* p, float v) {
    __hip_atomic_store(p, v, __ATOMIC_RELAXED, __HIP_MEMORY_SCOPE_AGENT);
}
__device__ __forceinline__ void gsti(int* p, int v) {
    __hip_atomic_store(p, v, __ATOMIC_RELAXED, __HIP_MEMORY_SCOPE_AGENT);
}

__device__ __forceinline__ int bucket_of(float v) {
    int k = (int)((v + 16.0f) * 128.0f);
    k = k < 0 ? 0 : k;
    k = k > (NB - 1) ? (NB - 1) : k;
    return k;
}

// Per-batch tree barrier: 64 contenders = 8 leaves x 8, release on 8 spread
// lines per batch. Batches decouple; max-arrival over 64 blocks, not 256.
__device__ __forceinline__ void gbar(int* wsi, int idx, int b, int t6) {
    __syncthreads();
    if (threadIdx.x == 0) {
        int leaf = t6 & 7;
        bool bcast = false;
        int old = __hip_atomic_fetch_add(wsi + LEAFo + ((idx * 4 + b) * 8 + leaf) * 32, 1,
                                         __ATOMIC_RELAXED, __HIP_MEMORY_SCOPE_AGENT);
        if (old == 7) {
            int m = __hip_atomic_fetch_add(wsi + MASTo + (idx * 4 + b) * 32, 1,
                                           __ATOMIC_RELAXED, __HIP_MEMORY_SCOPE_AGENT);
            if (m == 7) {
#pragma unroll
                for (int i = 0; i < 8; i++)
                    __hip_atomic_store(wsi + RELo + (b * 8 + i) * 32, idx + 1,
                                       __ATOMIC_RELAXED, __HIP_MEMORY_SCOPE_AGENT);
                bcast = true;
            }
        }
        if (!bcast) {
            const int* myrel = wsi + RELo + (b * 8 + leaf) * 32;
            while (__hip_atomic_load(myrel, __ATOMIC_RELAXED, __HIP_MEMORY_SCOPE_AGENT) <= idx)
                __builtin_amdgcn_s_sleep(1);
        }
    }
    __syncthreads();
}

// K0: weight prep (once, instead of 256x redundantly) + control-int zeroing.
// Stream order gives the producer->consumer barrier for free.
__global__ __launch_bounds__(1024) void k_prep(
        const float* __restrict__ Wq, const float* __restrict__ bq,
        const float* __restrict__ Wk, const float* __restrict__ bk,
        const float* __restrict__ wcq, const float* __restrict__ wck,
        const float* __restrict__ Wv, const float* __restrict__ bv,
        const float* __restrict__ Wg, float* __restrict__ ws) {
    int tid = threadIdx.x;
    // zero barrier state + histograms (replaces hipMemsetAsync dispatch)
    float4 z = make_float4(0.f, 0.f, 0.f, 0.f);
    for (int i = tid; i < ZERO_F4; i += 1024) ((float4*)ws)[i] = z;
    // small vectors
    if (tid < 64) {
        float s1 = 0.f, s2 = 0.f, s3 = 0.f;
        for (int o = 0; o < 16; o++) { s1 += wcq[o] * Wq[o * 64 + tid]; s2 += wck[o] * Wk[o * 64 + tid]; }
        for (int m = 0; m < 64; m++) s3 += Wg[tid * 64 + m] * bv[m];
        ws[WQEo + tid] = s1; ws[WKEo + tid] = s2; ws[BVGo + tid] = s3;
    } else if (tid == 64) {
        float s = 0.f; for (int o = 0; o < 16; o++) s += wcq[o] * bq[o]; ws[MISCo] = s;
    } else if (tid == 65) {
        float s = 0.f; for (int o = 0; o < 16; o++) s += wck[o] * bk[o]; ws[MISCo + 1] = s;
    }
    // Wvg = Wg @ Wv, stored as wt[c][o] (the layout the VG loop consumes)
    {
        int o = tid & 63, c0 = (tid >> 6) * 4;
        float acc[4];
#pragma unroll
        for (int k = 0; k < 4; k++) acc[k] = 0.f;
        for (int m = 0; m < 64; m++) {
            float wg = Wg[o * 64 + m];                         // per-lane, L1/L2 cached
            float4 a0 = *(const float4*)(Wv + m * 64 + c0);    // wave-uniform broadcast
            acc[0] += wg * a0.x; acc[1] += wg * a0.y; acc[2] += wg * a0.z; acc[3] += wg * a0.w;
        }
#pragma unroll
        for (int k = 0; k < 4; k++) ws[WTo + (c0 + k) * 64 + o] = acc[k];  // coalesced
    }
}

__global__ __launch_bounds__(1024, 1) void k_fused(
        const float* __restrict__ x,
        const float* __restrict__ bg,
        float* __restrict__ ws, float* __restrict__ out) {
    __shared__ float smem[13824];       // 55.3 KB
    int tid = threadIdx.x;
    int bid = blockIdx.x;
    int b = bid >> 6, t6 = bid & 63;
    int* wsi = (int*)ws;

    float myA = 0.f, myD = 0.f;         // a,d for pixel t6*64+tid (tid<64)
    int   myQ = 0;                      // snapped split chunk for own column j

    // ===== Phase A: stage x + precomputed weights, projections, VG =====
    {
        float* xt  = smem;              // [64][72] = 4608
        float* wt  = smem + 4608;       // [64][72]: wt[c][o] = Wvg[o][c]
        float* wqe = smem + 9216, *wke = smem + 9280;
        // x tile (coalesced float4)
        const float4* xb4 = (const float4*)(x + (size_t)b * 64 * 4096);
        {
            int c = tid >> 4, nl4 = tid & 15;
            float4 xr = xb4[c * 1024 + t6 * 16 + nl4];
            *(float4*)&xt[c * 72 + nl4 * 4] = xr;
        }
        // wt tile from workspace (16 KB, IC-broadcast across blocks)
        {
            int c = tid >> 4, o0 = (tid & 15) * 4;
            *(float4*)&wt[c * 72 + o0] = *(const float4*)&ws[WTo + c * 64 + o0];
        }
        if (tid < 64) { wqe[tid] = ws[WQEo + tid]; wke[tid] = ws[WKEo + tid]; }
        __syncthreads();
        if (tid < 64) {
            float s1 = ws[MISCo], s2 = ws[MISCo + 1];
            for (int c = 0; c < 64; c++) {
                float xv = xt[c * 72 + tid];
                s1 += wqe[c] * xv; s2 += wke[c] * xv;
            }
            myA = s1; myD = s2;                              // both stay in registers
            atomicAdd(&wsi[GHo + b * 4096 + bucket_of(s1)], 1);
        }
        {
            int o = tid & 63, nl0 = (tid >> 6) * 4;
            float acc[4];
            float bo = ws[BVGo + o];
#pragma unroll
            for (int k = 0; k < 4; k++) acc[k] = bo;
            for (int c = 0; c < 64; c++) {
                float wv = wt[c * 72 + o];                    // per-lane, conflict-free
                const float* xr2 = &xt[c * 72 + nl0];         // wave-uniform b128 bcast
#pragma unroll
                for (int k = 0; k < 4; k++) acc[k] += wv * xr2[k];
            }
#pragma unroll
            for (int k = 0; k < 4; k++)
                gst(&ws[VGo + ((size_t)(b * 4096) + t6 * 64 + nl0 + k) * 64 + o], acc[k]);
        }
    }
    gbar(wsi, 0, b, t6);

    // ===== Phase B: per-block shfl scan + scatter + own-column split lookup =====
    {
        unsigned int* hist = (unsigned int*)smem;          // [4096] bucket starts
        unsigned int* wtot = hist + 4096;                  // [16]
        int* gh_b = wsi + GHo + b * 4096;
#pragma unroll 4
        for (int i = tid; i < NB; i += 1024) hist[i] = (unsigned int)gh_b[i] & 0xFFFFu;
        __syncthreads();
        int lane = tid & 63, w = tid >> 6;
        unsigned int s = 0u; int base = tid * 4;
#pragma unroll
        for (int k = 0; k < 4; k++) s += hist[base + k];
        unsigned int inc = s;
        for (int off = 1; off < 64; off <<= 1) {
            unsigned int u = __shfl_up(inc, off);
            if (lane >= off) inc += u;
        }
        if (lane == 63) wtot[w] = inc;
        __syncthreads();
        unsigned int run = inc - s;
        for (int w2 = 0; w2 < w; w2++) run += wtot[w2];
        for (int k = 0; k < 4; k++) {
            unsigned int h = hist[base + k];
            hist[base + k] = run;       // hist now holds bucket starts
            run += h;
        }
        __syncthreads();
        if (tid < 64) {
            // split lookup for own output column j = t6*64+tid (d in register)
            myQ = ((int)hist[bucket_of(-myD)] + 32) >> 6;
            // scatter own pixel; cursor packed in GH high bits
            int i = t6 * 64 + tid;
            int kb = bucket_of(myA);
            int old = atomicAdd(&gh_b[kb], 0x10000);
            int r = (int)hist[kb] + (old >> 16);
            gst(&ws[ASo + b * 4096 + r], myA);
            gsti((int*)ws + PERMo + b * 4096 + r, i);
        }
    }
    gbar(wsi, 1, b, t6);

    // ===== Phase C: chunk partials (cached reads, sc writes), 16 waves x 4 rows =====
    {
        int c = tid & 63, w = tid >> 6;
        int r0 = t6 * 64 + w * 4;
        const int* perm = (const int*)ws + PERMo;
        int pk[4]; float avs[4], wvs[4];
#pragma unroll
        for (int k = 0; k < 4; k++) pk[k] = perm[b * 4096 + r0 + k];
#pragma unroll
        for (int k = 0; k < 4; k++) avs[k] = ws[ASo + b * 4096 + r0 + k];
#pragma unroll
        for (int k = 0; k < 4; k++) wvs[k] = ws[VGo + ((size_t)(b * 4096) + pk[k]) * 64 + c];
        float s1 = 0.f, s2 = 0.f, s3 = 0.f, sea_w = 0.f, sa_w = 0.f;
#pragma unroll
        for (int k = 0; k < 4; k++) {
            float ea = expf(avs[k]);
            s1 += wvs[k]; s2 += wvs[k] * ea; s3 += wvs[k] * avs[k];
            sea_w += ea; sa_w += avs[k];
        }
        float* partL = smem;            // [16][3][64] = 3072
        float* wsc   = smem + 3072;     // [32]
        partL[(w * 3 + 0) * 64 + c] = s1;
        partL[(w * 3 + 1) * 64 + c] = s2;
        partL[(w * 3 + 2) * 64 + c] = s3;
        if (c == 0) { wsc[w] = sea_w; wsc[16 + w] = sa_w; }
        __syncthreads();
        if (tid < 192) {
            int g = tid >> 6, cc = tid & 63;
            float sum = 0.f;
#pragma unroll
            for (int ww = 0; ww < 16; ww++) sum += partL[(ww * 3 + g) * 64 + cc];
            gst(&ws[Po + (b * 64 + t6) * 192 + tid], sum);
        } else if (tid == 192) {
            float sum = 0.f;
#pragma unroll
            for (int ww = 0; ww < 16; ww++) sum += wsc[ww];
            gst(&ws[PSEAo + b * 64 + t6], sum);
        } else if (tid == 193) {
            float sum = 0.f;
#pragma unroll
            for (int ww = 0; ww < 16; ww++) sum += wsc[16 + ww];
            gst(&ws[PSAo + b * 64 + t6], sum);
        }
    }
    gbar(wsi, 2, b, t6);

    // ===== Phase F: per-block chunk-prefix (reg prefetch) + output =====
    {
        float* CP     = smem;                  // [65][193] = 12545
        float* cpsea  = smem + 12545;          // [65]
        float* cpsa   = smem + 12610;          // [65]
        float* djs    = smem + 12675;          // [64]
        float* edjs   = smem + 12739;          // [64]
        float* invden = smem + 12803;          // [64]
        int*   qarr   = (int*)(smem + 12867);  // [64]
        float* bgs    = smem + 12931;          // [64]
        if (tid < 192) {
            float v[64];
#pragma unroll
            for (int ch = 0; ch < 64; ch++) v[ch] = ws[Po + b * 12288 + ch * 192 + tid]; // cached
            float r = 0.f;
#pragma unroll
            for (int q = 0; q < 64; q++) { CP[q * 193 + tid] = r; r += v[q]; }
            CP[64 * 193 + tid] = r;
        } else if (tid == 192) {
            float v[64];
#pragma unroll
            for (int ch = 0; ch < 64; ch++) v[ch] = ws[PSEAo + b * 64 + ch];
            float r = 0.f;
#pragma unroll
            for (int q = 0; q < 64; q++) { cpsea[q] = r; r += v[q]; }
            cpsea[64] = r;
        } else if (tid == 193) {
            float v[64];
#pragma unroll
            for (int ch = 0; ch < 64; ch++) v[ch] = ws[PSAo + b * 64 + ch];
            float r = 0.f;
#pragma unroll
            for (int q = 0; q < 64; q++) { cpsa[q] = r; r += v[q]; }
            cpsa[64] = r;
        }
        if (tid < 64) bgs[tid] = bg[tid];
        __syncthreads();
        int j0 = t6 * 64;
        if (tid < 64) {
            float dj = myD;
            float edj = expf(dj);
            int q = myQ;
            float den = 1.5f * ((cpsa[64] - cpsa[q]) + dj * (float)(4096 - 64 * q)
                                - (float)(64 * q) + edj * cpsea[q]);
            qarr[tid] = q; djs[tid] = dj; edjs[tid] = edj; invden[tid] = 1.0f / den;
        }
        __syncthreads();
        {
            int jl = tid & 63, cq = tid >> 6;
            float dj = djs[jl], edj = edjs[jl], inv = invden[jl];
            int qb = qarr[jl] * 193;
#pragma unroll
            for (int cc = cq; cc < 64; cc += 16) {
                float c1 = CP[qb + cc], c2 = CP[qb + 64 + cc], c3 = CP[qb + 128 + cc];
                float t1 = CP[64 * 193 + cc], t3 = CP[64 * 193 + 128 + cc];
                float num = (t3 - c3) + dj * t1 - (1.0f + dj) * c1 + edj * c2;
                out[((size_t)(b * 64 + cc)) * 4096 + j0 + jl] = num * inv + bgs[cc];
            }
        }
    }
}

extern "C" void kernel_launch(void* const* d_in, const int* in_sizes, int n_in,
                              void* d_out, int out_size, void* d_ws, size_t ws_size,
                              hipStream_t stream) {
    const float* x   = (const float*)d_in[0];
    const float* Wq  = (const float*)d_in[1];
    const float* bq  = (const float*)d_in[2];
    const float* Wk  = (const float*)d_in[3];
    const float* bk  = (const float*)d_in[4];
    const float* wcq = (const float*)d_in[5];
    const float* wck = (const float*)d_in[6];
    const float* Wv  = (const float*)d_in[7];
    const float* bv  = (const float*)d_in[8];
    const float* Wg  = (const float*)d_in[9];
    const float* bg  = (const float*)d_in[10];
    float* ws  = (float*)d_ws;
    float* out = (float*)d_out;

    k_prep<<<1, 1024, 0, stream>>>(Wq, bq, Wk, bk, wcq, wck, Wv, bv, Wg, ws);
    k_fused<<<256, 1024, 0, stream>>>(x, bg, ws, out);
}